// Round 10
// baseline (48.893 us; speedup 1.0000x reference)
//
#include <hip/hip_runtime.h>
#include <hip/hip_fp16.h>

// Compress70, round 10.
// Algorithm identical to round 9 (fp16 transposed workspaces, masked
// wave-uniform gathers, fused LDS un-transpose stores). Scheduling only:
//  - prep: LDS halved to 16.6KB via two sequential chunks -> 1536 blocks
//    all-resident (was 4/CU: 1024+512 rounds, 25% tail).
//  - mains: persistent 1536 blocks x 2 same-type units, 6 blocks/CU
//    all-resident, zero drain tail (was 3072 at 9/CU: 2304+768).

#define N2 (2*128*128*128)   // 4194304
#define N1 (2*64*256*256)    // 8388608
#define WS_NEED ((size_t)(N2 + N1) * 2)   // fp16 workspaces

union H4 { float2 f2; __half2 h2[2]; };

// ---------------- fused input transposes (fp32 -> fp16), chunked ----------
__global__ __launch_bounds__(256) void prep_kernel(
    const float* __restrict__ lv1, const float* __restrict__ lv2,
    __half* __restrict__ ws2T, __half* __restrict__ ws1T)
{
    __shared__ float lds[4160];      // lv2: 32*129=4128; lv1: 64*65=4160
    int bid  = blockIdx.x;
    int tid  = threadIdx.x;
    int lane = tid & 63;
    int wave = tid >> 6;
    if (bid < 512) {
        // lv2 [b][c][p] -> ws2T [b][p][128c] (half), two 32-px chunks
        int b  = bid >> 8;
        int p0 = (bid & 255) << 6;
        const float* src  = lv2 + (long)b * (128 * 16384);
        __half*      dstp = ws2T + ((long)b << 21) + (long)p0 * 128;
        int pl = tid & 31, cb = tid >> 5;
#pragma unroll
        for (int ch = 0; ch < 2; ++ch) {
            int pb = ch << 5;
#pragma unroll 4
            for (int it = 0; it < 16; ++it) {
                int c = it * 8 + cb;
                lds[pl * 129 + c] = src[c * 16384 + p0 + pb + pl];
            }
            __syncthreads();
#pragma unroll
            for (int it = 0; it < 8; ++it) {
                int p = it * 4 + wave;
                __half2 h = __floats2half2_rn(lds[p * 129 + 2 * lane],
                                              lds[p * 129 + 2 * lane + 1]);
                *(__half2*)(dstp + (long)(pb + p) * 128 + 2 * lane) = h;
            }
            __syncthreads();
        }
    } else {
        // lv1 [b][c][sy][sx] -> ws1T blocked (half), two 32-sx chunks
        // BL1(b,sy,sx,c) = (b<<22)+((sy>>1)<<15)+((sx>>1)<<8)+(c<<2)+((sy&1)<<1)+(sx&1)
        int bb  = bid - 512;
        int sxc = bb & 3;
        int sy2 = (bb >> 2) & 127;
        int b   = bb >> 9;
        const float* src  = lv1 + ((long)b << 22);
        __half*      dsth = ws1T + ((long)b << 22) + ((long)sy2 << 15) + (sxc << 13);
        int sy0 = sy2 * 2, sx0 = sxc * 64;
        int l32 = tid & 31, rb = tid >> 5;
#pragma unroll
        for (int ch = 0; ch < 2; ++ch) {
#pragma unroll 4
            for (int it = 0; it < 16; ++it) {
                int row = it * 8 + rb;       // (c, r)
                int c = row >> 1, r = row & 1;
                lds[(r * 32 + l32) * 65 + c] =
                    src[((long)c << 16) + ((sy0 + r) << 8) + sx0 + ch * 32 + l32];
            }
            __syncthreads();
#pragma unroll
            for (int it = 0; it < 4; ++it) {
                int g = it * 4 + wave;       // local sx-pair 0..15
                H4 w;
                w.h2[0] = __floats2half2_rn(lds[(2 * g) * 65 + lane],
                                            lds[(2 * g + 1) * 65 + lane]);
                w.h2[1] = __floats2half2_rn(lds[(32 + 2 * g) * 65 + lane],
                                            lds[(32 + 2 * g + 1) * 65 + lane]);
                *(float2*)(dsth + ((16 * ch + g) << 8) + (lane << 2)) = w.f2;
            }
            __syncthreads();
        }
    }
}

// ---------------- main gather unit bodies ----------------
__device__ __forceinline__ void main2_unit(
    int u, int tid, const __half* __restrict__ ws2T,
    const int* __restrict__ hidx, float* __restrict__ out,
    float* lds, int* sidx)
{
    int lane = tid & 63, wave = tid >> 6;
    int p0 = u * 32;                 // 32 consecutive pixels, one (b,y) row seg
    int b  = p0 >> 14;
    int y  = (p0 >> 7) & 127;
    int x0 = p0 & 127;
    const int*    hb  = hidx + (b << 14);
    const __half* src = ws2T + ((long)b << 21);
    if (tid < 102) {                 // rows y-1..y+1, cols x0-1..x0+32
        int r = tid / 34, j = tid - r * 34;
        int a = y - 1 + r, e = x0 - 1 + j;
        int ok = ((unsigned)a < 128u) & ((unsigned)e < 128u);
        sidx[tid] = hb[ok ? ((a << 7) + e) : 0];
    }
    __syncthreads();
    int lane2 = lane << 1;
#pragma unroll
    for (int ii = 0; ii < 4; ++ii) { // 4 pixel-pairs per wave
        int XlA = (wave << 3) + (ii << 1);
        int xA  = x0 + XlA;
        int   offA[9], offB[9];
        float mA[9], mB[9];
#pragma unroll
        for (int da = -1; da <= 1; ++da) {
#pragma unroll
            for (int de = -1; de <= 1; ++de) {
                int k = (da + 1) * 3 + (de + 1);
                int a = y + da;
                {
                    int e  = xA + de;
                    int vj = ((unsigned)a < 128u) & ((unsigned)e < 128u);
                    int p  = __builtin_amdgcn_readfirstlane(
                                 sidx[(da + 1) * 34 + XlA + de + 1]);
                    int sr = (p >> 7) - da, sc = (p & 127) - de;
                    int vs = ((unsigned)sr < 128u) & ((unsigned)sc < 128u);
                    mA[k]   = (vj & vs) ? (1.f / 9.f) : 0.f;
                    offA[k] = vs ? (((sr << 7) + sc) << 7) : 0;
                }
                {
                    int e  = xA + 1 + de;
                    int vj = ((unsigned)a < 128u) & ((unsigned)e < 128u);
                    int p  = __builtin_amdgcn_readfirstlane(
                                 sidx[(da + 1) * 34 + XlA + de + 2]);
                    int sr = (p >> 7) - da, sc = (p & 127) - de;
                    int vs = ((unsigned)sr < 128u) & ((unsigned)sc < 128u);
                    mB[k]   = (vj & vs) ? (1.f / 9.f) : 0.f;
                    offB[k] = vs ? (((sr << 7) + sc) << 7) : 0;
                }
            }
        }
        __half2 vA[9], vB[9];
#pragma unroll
        for (int k = 0; k < 9; ++k) {
            vA[k] = *(const __half2*)(src + offA[k] + lane2);
            vB[k] = *(const __half2*)(src + offB[k] + lane2);
        }
        __builtin_amdgcn_sched_barrier(0);
        float axA = 0.f, ayA = 0.f, axB = 0.f, ayB = 0.f;
#pragma unroll
        for (int k = 0; k < 9; ++k) {
            float2 fa = __half22float2(vA[k]);
            float2 fb = __half22float2(vB[k]);
            axA += fa.x * mA[k]; ayA += fa.y * mA[k];
            axB += fb.x * mB[k]; ayB += fb.y * mB[k];
        }
        lds[XlA * 129 + lane2]           = axA;
        lds[XlA * 129 + lane2 + 1]       = ayA;
        lds[(XlA + 1) * 129 + lane2]     = axB;
        lds[(XlA + 1) * 129 + lane2 + 1] = ayB;
    }
    __syncthreads();
    int xl = tid & 31, cb = tid >> 5;
#pragma unroll
    for (int it = 0; it < 16; ++it) {
        int c = it * 8 + cb;
        out[((long)(b * 128 + c) << 14) + (y << 7) + x0 + xl] =
            lds[xl * 129 + c];
    }
}

__device__ __forceinline__ void main1_unit(
    int u, int tid, const __half* __restrict__ ws1T,
    const int* __restrict__ hidx, float* __restrict__ out1,
    float* lds, int* sidx)
{
    int lane = tid & 63, wave = tid >> 6;
    int t0  = u * 16;                // 16 consecutive 2x2 tiles, one (b,uy) seg
    int b   = t0 >> 14;
    int uy  = (t0 >> 7) & 127;
    int ux0 = t0 & 127;
    const int*    hb  = hidx + (b << 14);
    const __half* src = ws1T + ((long)b << 22);
    if (tid < 54) {                  // rows uy-1..uy+1, cols ux0-1..ux0+16
        int r = tid / 18, j = tid - r * 18;
        int jy = uy - 1 + r, jx = ux0 - 1 + j;
        int ok = ((unsigned)jy < 128u) & ((unsigned)jx < 128u);
        sidx[tid] = hb[ok ? ((jy << 7) + jx) : 0];
    }
    __syncthreads();
    int lane4 = lane << 2;
#pragma unroll
    for (int ii = 0; ii < 2; ++ii) { // 2 tile-pairs per wave
        int tiA = (wave << 2) + (ii << 1);
        int uxA = ux0 + tiA;
        int   offA[9], offB[9];
        float mA[9], mB[9];
#pragma unroll
        for (int ka = 0; ka < 3; ++ka) {
#pragma unroll
            for (int kb = 0; kb < 3; ++kb) {
                int k  = ka * 3 + kb;
                int jy = uy + 1 - ka;
                int vy = ((unsigned)jy < 128u);
                {
                    int jx = uxA + 1 - kb;
                    int vj = vy & ((unsigned)jx < 128u);
                    int p  = __builtin_amdgcn_readfirstlane(
                                 sidx[(2 - ka) * 18 + tiA + 2 - kb]);
                    int ry = (p >> 7) + ka - 1, rx = (p & 127) + kb - 1;
                    int vs = ((unsigned)ry < 128u) & ((unsigned)rx < 128u);
                    mA[k]   = (vj & vs) ? (1.f / 9.f) : 0.f;
                    offA[k] = vs ? ((ry << 15) + (rx << 8)) : 0;
                }
                {
                    int jx = uxA + 2 - kb;
                    int vj = vy & ((unsigned)jx < 128u);
                    int p  = __builtin_amdgcn_readfirstlane(
                                 sidx[(2 - ka) * 18 + tiA + 3 - kb]);
                    int ry = (p >> 7) + ka - 1, rx = (p & 127) + kb - 1;
                    int vs = ((unsigned)ry < 128u) & ((unsigned)rx < 128u);
                    mB[k]   = (vj & vs) ? (1.f / 9.f) : 0.f;
                    offB[k] = vs ? ((ry << 15) + (rx << 8)) : 0;
                }
            }
        }
        float2 rA[9], rB[9];         // 4 halfs each (c=lane, 2x2 spatial)
#pragma unroll
        for (int k = 0; k < 9; ++k) {
            rA[k] = *(const float2*)(src + offA[k] + lane4);
            rB[k] = *(const float2*)(src + offB[k] + lane4);
        }
        __builtin_amdgcn_sched_barrier(0);
        float4 aA = make_float4(0.f, 0.f, 0.f, 0.f);
        float4 aB = make_float4(0.f, 0.f, 0.f, 0.f);
#pragma unroll
        for (int k = 0; k < 9; ++k) {
            H4 ua, ub; ua.f2 = rA[k]; ub.f2 = rB[k];
            float2 alo = __half22float2(ua.h2[0]);
            float2 ahi = __half22float2(ua.h2[1]);
            float2 blo = __half22float2(ub.h2[0]);
            float2 bhi = __half22float2(ub.h2[1]);
            aA.x += alo.x * mA[k]; aA.y += alo.y * mA[k];
            aA.z += ahi.x * mA[k]; aA.w += ahi.y * mA[k];
            aB.x += blo.x * mB[k]; aB.y += blo.y * mB[k];
            aB.z += bhi.x * mB[k]; aB.w += bhi.y * mB[k];
        }
        int XA = tiA * 2;            // lds [r][X<32][c pad65]
        lds[(XA) * 65 + lane]          = aA.x;
        lds[(XA + 1) * 65 + lane]      = aA.y;
        lds[(32 + XA) * 65 + lane]     = aA.z;
        lds[(32 + XA + 1) * 65 + lane] = aA.w;
        lds[(XA + 2) * 65 + lane]      = aB.x;
        lds[(XA + 3) * 65 + lane]      = aB.y;
        lds[(32 + XA + 2) * 65 + lane] = aB.z;
        lds[(32 + XA + 3) * 65 + lane] = aB.w;
    }
    __syncthreads();
    int Y0 = uy * 2, X0 = ux0 * 2;
    float* dst = out1 + ((long)b << 22);
    int xl = tid & 31, rsel = tid >> 5;
#pragma unroll
    for (int it = 0; it < 16; ++it) {
        int row = it * 8 + rsel;     // (c, r)
        int c = row >> 1, r = row & 1;
        dst[((long)c << 16) + ((Y0 + r) << 8) + X0 + xl] =
            lds[(r * 32 + xl) * 65 + c];
    }
}

// ---------------- persistent fused mains: 1536 blocks x 2 units -----------
__global__ __launch_bounds__(256) void mains_kernel(
    const __half* __restrict__ ws2T, const __half* __restrict__ ws1T,
    const int* __restrict__ hidx, float* __restrict__ out)
{
    __shared__ float lds[4160];
    __shared__ int   sidx[102];
    int bid  = blockIdx.x;
    int base = (bid & 7) * 384 + ((bid >> 3) << 1);   // even; bijective XCD-chunked
    int tid  = threadIdx.x;
    if (base < 1024) {
        main2_unit(base,     tid, ws2T, hidx, out, lds, sidx);
        __syncthreads();
        main2_unit(base + 1, tid, ws2T, hidx, out, lds, sidx);
    } else {
        float* out1 = out + N2;
        main1_unit(base - 1024, tid, ws1T, hidx, out1, lds, sidx);
        __syncthreads();
        main1_unit(base - 1023, tid, ws1T, hidx, out1, lds, sidx);
    }
}

// ---------------- round-1 scalar fallback ----------------
__global__ __launch_bounds__(256) void fb2_kernel(
    const float* __restrict__ lv2, const int* __restrict__ hidx,
    float* __restrict__ out)
{
    int t = blockIdx.x * 256 + threadIdx.x;
    int x  = t & 127;
    int y  = (t >> 7) & 127;
    int bc = t >> 14;
    int b  = t >> 21;
    const int*   hb  = hidx + (b << 14);
    const float* src = lv2 + ((long)bc << 14);
    float acc = 0.f;
#pragma unroll
    for (int da = -1; da <= 1; ++da) {
        int a = y + da;
        if ((unsigned)a >= 128u) continue;
#pragma unroll
        for (int de = -1; de <= 1; ++de) {
            int e = x + de;
            if ((unsigned)e >= 128u) continue;
            int p  = hb[(a << 7) + e];
            int sr = (p >> 7) - da;
            int sc = (p & 127) - de;
            if ((unsigned)sr < 128u && (unsigned)sc < 128u)
                acc += src[(sr << 7) + sc];
        }
    }
    out[t] = acc * (1.f / 9.f);
}

__global__ __launch_bounds__(256) void fb1_kernel(
    const float* __restrict__ lv1, const int* __restrict__ hidx,
    float* __restrict__ out)
{
    int t = blockIdx.x * 256 + threadIdx.x;
    int X  = t & 255;
    int Y  = (t >> 8) & 255;
    int bc = t >> 16;
    int b  = t >> 22;
    const int*   hb  = hidx + (b << 14);
    const float* src = lv1 + ((long)bc << 16);
    int jyh = (Y + 2) >> 1;
    int jxh = (X + 2) >> 1;
    float acc = 0.f;
#pragma unroll
    for (int ka = 0; ka < 3; ++ka) {
        int jy = jyh - ka;
        if ((unsigned)jy >= 128u) continue;
        int dy = Y - 2 * jy;
#pragma unroll
        for (int kb = 0; kb < 3; ++kb) {
            int jx = jxh - kb;
            if ((unsigned)jx >= 128u) continue;
            int dx = X - 2 * jx;
            int p  = hb[(jy << 7) + jx];
            int sr = 2 * (p >> 7) + dy;
            int sc = 2 * (p & 127) + dx;
            if ((unsigned)sr < 256u && (unsigned)sc < 256u)
                acc += src[(sr << 8) + sc];
        }
    }
    out[t] = acc * (1.f / 9.f);
}

extern "C" void kernel_launch(void* const* d_in, const int* in_sizes, int n_in,
                              void* d_out, int out_size, void* d_ws, size_t ws_size,
                              hipStream_t stream)
{
    const float* lv1  = (const float*)d_in[0];
    const float* lv2  = (const float*)d_in[1];
    const int*   hidx = (const int*)d_in[2];
    float* out = (float*)d_out;

    if (ws_size >= WS_NEED) {
        __half* ws2T = (__half*)d_ws;
        __half* ws1T = ws2T + N2;
        prep_kernel<<<1536, 256, 0, stream>>>(lv1, lv2, ws2T, ws1T);
        mains_kernel<<<1536, 256, 0, stream>>>(ws2T, ws1T, hidx, out);
    } else {
        fb2_kernel<<<N2 / 256, 256, 0, stream>>>(lv2, hidx, out);
        fb1_kernel<<<N1 / 256, 256, 0, stream>>>(lv1, hidx, out + N2);
    }
}

// Round 11
// 46.364 us; speedup vs baseline: 1.0545x; 1.0545x over previous
//
#include <hip/hip_runtime.h>
#include <hip/hip_fp16.h>

// Compress70, final (= round 9, best measured 46.4us; round-10 scheduling
// variants regressed). fp16 transposed workspaces, masked wave-uniform
// gathers via LDS-staged h_index, fused LDS un-transpose stores.
// Roofline: mains bound by ~22G random L2-miss lines/s (invariant across
// rounds 4-10); fp16 minimizes lines (~610K); residual 3x duplication is
// uncapturable (random-collision reuse, disjoint-row consumers).
// Model floor ~42-45us.

#define N2 (2*128*128*128)   // 4194304
#define N1 (2*64*256*256)    // 8388608
#define WS_NEED ((size_t)(N2 + N1) * 2)   // fp16 workspaces

union H4 { float2 f2; __half2 h2[2]; };

// ---------------- fused input transposes (fp32 -> fp16) ----------------
__global__ __launch_bounds__(256) void prep_kernel(
    const float* __restrict__ lv1, const float* __restrict__ lv2,
    __half* __restrict__ ws2T, __half* __restrict__ ws1T)
{
    __shared__ float lds[8320];
    int bid  = blockIdx.x;
    int lane = threadIdx.x & 63;
    int wid  = threadIdx.x >> 6;
    if (bid < 512) {
        // lv2 [b][c][p] -> ws2T [b][p][128c] (half)
        int b  = bid >> 8;
        int p0 = (bid & 255) << 6;
        const float* src = lv2 + (long)b * (128 * 16384);
#pragma unroll 4
        for (int it = 0; it < 32; ++it) {
            int c = it * 4 + wid;
            lds[c * 65 + lane] = src[c * 16384 + p0 + lane];
        }
        __syncthreads();
        __half* dsth = ws2T + ((long)b << 21) + (long)p0 * 128;
        int c2 = threadIdx.x & 63;       // channel pair
        int pw = threadIdx.x >> 6;       // 4 pixels per pass
#pragma unroll 4
        for (int it = 0; it < 16; ++it) {
            int p = it * 4 + pw;
            __half2 h = __floats2half2_rn(lds[(2 * c2) * 65 + p],
                                          lds[(2 * c2 + 1) * 65 + p]);
            *((__half2*)dsth + p * 64 + c2) = h;
        }
    } else {
        // lv1 [b][c][sy][sx] -> ws1T blocked (half):
        // (b<<22)+((sy>>1)<<15)+((sx>>1)<<8)+(c<<2)+((sy&1)<<1)+(sx&1)
        int bb  = bid - 512;
        int sxc = bb & 3;
        int sy2 = (bb >> 2) & 127;
        int b   = bb >> 9;
        const float* src = lv1 + ((long)b << 22);
        int sy0 = sy2 * 2, sx0 = sxc * 64;
#pragma unroll 4
        for (int it = 0; it < 32; ++it) {
            int row = it * 4 + wid;
            int c = row >> 1, r = row & 1;
            lds[(r * 64 + lane) * 65 + c] =
                src[((long)c << 16) + ((sy0 + r) << 8) + sx0 + lane];
        }
        __syncthreads();
        __half* dsth = ws1T + ((long)b << 22) + ((long)sy2 << 15) + (sxc << 13);
#pragma unroll
        for (int it = 0; it < 8; ++it) {
            int g = it * 4 + wid;
            H4 w;
            w.h2[0] = __floats2half2_rn(lds[(2 * g) * 65 + lane],
                                        lds[(2 * g + 1) * 65 + lane]);
            w.h2[1] = __floats2half2_rn(lds[(64 + 2 * g) * 65 + lane],
                                        lds[(64 + 2 * g + 1) * 65 + lane]);
            *(float2*)(dsth + (g << 8) + (lane << 2)) = w.f2;
        }
    }
}

// ---------------- fused main gathers (fp16 sources) ----------------
__global__ __launch_bounds__(256) void mains_kernel(
    const __half* __restrict__ ws2T, const __half* __restrict__ ws1T,
    const int* __restrict__ hidx, float* __restrict__ out)
{
    __shared__ float lds[4160];
    __shared__ int   sidx[102];
    int bid  = blockIdx.x;
    int wid_all = (bid & 7) * 384 + (bid >> 3);   // bijective XCD-chunked
    int tid  = threadIdx.x;
    int lane = tid & 63;
    int wave = tid >> 6;

    if (wid_all < 1024) {
        // ---- main2: 32 consecutive pixels (one b,y row segment) ----
        int p0 = wid_all * 32;
        int b  = p0 >> 14;
        int y  = (p0 >> 7) & 127;
        int x0 = p0 & 127;
        const int*    hb  = hidx + (b << 14);
        const __half* src = ws2T + ((long)b << 21);
        if (tid < 102) {                 // rows y-1..y+1, cols x0-1..x0+32
            int r = tid / 34, j = tid - r * 34;
            int a = y - 1 + r, e = x0 - 1 + j;
            int ok = ((unsigned)a < 128u) & ((unsigned)e < 128u);
            sidx[tid] = hb[ok ? ((a << 7) + e) : 0];
        }
        __syncthreads();
        int lane2 = lane << 1;
#pragma unroll
        for (int ii = 0; ii < 4; ++ii) { // 4 pixel-pairs per wave
            int XlA = (wave << 3) + (ii << 1);
            int xA  = x0 + XlA;
            int   offA[9], offB[9];
            float mA[9], mB[9];
#pragma unroll
            for (int da = -1; da <= 1; ++da) {
#pragma unroll
                for (int de = -1; de <= 1; ++de) {
                    int k = (da + 1) * 3 + (de + 1);
                    int a = y + da;
                    {
                        int e  = xA + de;
                        int vj = ((unsigned)a < 128u) & ((unsigned)e < 128u);
                        int p  = __builtin_amdgcn_readfirstlane(
                                     sidx[(da + 1) * 34 + XlA + de + 1]);
                        int sr = (p >> 7) - da, sc = (p & 127) - de;
                        int vs = ((unsigned)sr < 128u) & ((unsigned)sc < 128u);
                        mA[k]   = (vj & vs) ? (1.f / 9.f) : 0.f;
                        offA[k] = vs ? (((sr << 7) + sc) << 7) : 0;
                    }
                    {
                        int e  = xA + 1 + de;
                        int vj = ((unsigned)a < 128u) & ((unsigned)e < 128u);
                        int p  = __builtin_amdgcn_readfirstlane(
                                     sidx[(da + 1) * 34 + XlA + de + 2]);
                        int sr = (p >> 7) - da, sc = (p & 127) - de;
                        int vs = ((unsigned)sr < 128u) & ((unsigned)sc < 128u);
                        mB[k]   = (vj & vs) ? (1.f / 9.f) : 0.f;
                        offB[k] = vs ? (((sr << 7) + sc) << 7) : 0;
                    }
                }
            }
            __half2 vA[9], vB[9];
#pragma unroll
            for (int k = 0; k < 9; ++k) {
                vA[k] = *(const __half2*)(src + offA[k] + lane2);
                vB[k] = *(const __half2*)(src + offB[k] + lane2);
            }
            __builtin_amdgcn_sched_barrier(0);
            float axA = 0.f, ayA = 0.f, axB = 0.f, ayB = 0.f;
#pragma unroll
            for (int k = 0; k < 9; ++k) {
                float2 fa = __half22float2(vA[k]);
                float2 fb = __half22float2(vB[k]);
                axA += fa.x * mA[k]; ayA += fa.y * mA[k];
                axB += fb.x * mB[k]; ayB += fb.y * mB[k];
            }
            lds[XlA * 129 + lane2]           = axA;
            lds[XlA * 129 + lane2 + 1]       = ayA;
            lds[(XlA + 1) * 129 + lane2]     = axB;
            lds[(XlA + 1) * 129 + lane2 + 1] = ayB;
        }
        __syncthreads();
        int xl = tid & 31, cb = tid >> 5;
#pragma unroll
        for (int it = 0; it < 16; ++it) {
            int c = it * 8 + cb;
            out[((long)(b * 128 + c) << 14) + (y << 7) + x0 + xl] =
                lds[xl * 129 + c];
        }
    } else {
        // ---- main1: 16 consecutive 2x2 tiles (one b,uy row segment) ----
        int w1  = wid_all - 1024;
        int t0  = w1 * 16;
        int b   = t0 >> 14;
        int uy  = (t0 >> 7) & 127;
        int ux0 = t0 & 127;
        const int*    hb  = hidx + (b << 14);
        const __half* src = ws1T + ((long)b << 22);
        float* out1 = out + N2;
        if (tid < 54) {                  // rows uy-1..uy+1, cols ux0-1..ux0+16
            int r = tid / 18, j = tid - r * 18;
            int jy = uy - 1 + r, jx = ux0 - 1 + j;
            int ok = ((unsigned)jy < 128u) & ((unsigned)jx < 128u);
            sidx[tid] = hb[ok ? ((jy << 7) + jx) : 0];
        }
        __syncthreads();
        int lane4 = lane << 2;
#pragma unroll
        for (int ii = 0; ii < 2; ++ii) { // 2 tile-pairs per wave
            int tiA = (wave << 2) + (ii << 1);
            int uxA = ux0 + tiA;
            int   offA[9], offB[9];
            float mA[9], mB[9];
#pragma unroll
            for (int ka = 0; ka < 3; ++ka) {
#pragma unroll
                for (int kb = 0; kb < 3; ++kb) {
                    int k  = ka * 3 + kb;
                    int jy = uy + 1 - ka;
                    int vy = ((unsigned)jy < 128u);
                    {
                        int jx = uxA + 1 - kb;
                        int vj = vy & ((unsigned)jx < 128u);
                        int p  = __builtin_amdgcn_readfirstlane(
                                     sidx[(2 - ka) * 18 + tiA + 2 - kb]);
                        int ry = (p >> 7) + ka - 1, rx = (p & 127) + kb - 1;
                        int vs = ((unsigned)ry < 128u) & ((unsigned)rx < 128u);
                        mA[k]   = (vj & vs) ? (1.f / 9.f) : 0.f;
                        offA[k] = vs ? ((ry << 15) + (rx << 8)) : 0;
                    }
                    {
                        int jx = uxA + 2 - kb;
                        int vj = vy & ((unsigned)jx < 128u);
                        int p  = __builtin_amdgcn_readfirstlane(
                                     sidx[(2 - ka) * 18 + tiA + 3 - kb]);
                        int ry = (p >> 7) + ka - 1, rx = (p & 127) + kb - 1;
                        int vs = ((unsigned)ry < 128u) & ((unsigned)rx < 128u);
                        mB[k]   = (vj & vs) ? (1.f / 9.f) : 0.f;
                        offB[k] = vs ? ((ry << 15) + (rx << 8)) : 0;
                    }
                }
            }
            float2 rA[9], rB[9];         // 4 halfs each (c=lane, 2x2 spatial)
#pragma unroll
            for (int k = 0; k < 9; ++k) {
                rA[k] = *(const float2*)(src + offA[k] + lane4);
                rB[k] = *(const float2*)(src + offB[k] + lane4);
            }
            __builtin_amdgcn_sched_barrier(0);
            float4 aA = make_float4(0.f, 0.f, 0.f, 0.f);
            float4 aB = make_float4(0.f, 0.f, 0.f, 0.f);
#pragma unroll
            for (int k = 0; k < 9; ++k) {
                H4 ua, ub; ua.f2 = rA[k]; ub.f2 = rB[k];
                float2 alo = __half22float2(ua.h2[0]);
                float2 ahi = __half22float2(ua.h2[1]);
                float2 blo = __half22float2(ub.h2[0]);
                float2 bhi = __half22float2(ub.h2[1]);
                aA.x += alo.x * mA[k]; aA.y += alo.y * mA[k];
                aA.z += ahi.x * mA[k]; aA.w += ahi.y * mA[k];
                aB.x += blo.x * mB[k]; aB.y += blo.y * mB[k];
                aB.z += bhi.x * mB[k]; aB.w += bhi.y * mB[k];
            }
            int XA = tiA * 2;            // lds [r][X<32][c pad65]
            lds[(XA) * 65 + lane]          = aA.x;
            lds[(XA + 1) * 65 + lane]      = aA.y;
            lds[(32 + XA) * 65 + lane]     = aA.z;
            lds[(32 + XA + 1) * 65 + lane] = aA.w;
            lds[(XA + 2) * 65 + lane]      = aB.x;
            lds[(XA + 3) * 65 + lane]      = aB.y;
            lds[(32 + XA + 2) * 65 + lane] = aB.z;
            lds[(32 + XA + 3) * 65 + lane] = aB.w;
        }
        __syncthreads();
        int Y0 = uy * 2, X0 = ux0 * 2;
        float* dst = out1 + ((long)b << 22);
        int xl = tid & 31, rsel = tid >> 5;
#pragma unroll
        for (int it = 0; it < 16; ++it) {
            int row = it * 8 + rsel;     // (c, r)
            int c = row >> 1, r = row & 1;
            dst[((long)c << 16) + ((Y0 + r) << 8) + X0 + xl] =
                lds[(r * 32 + xl) * 65 + c];
        }
    }
}

// ---------------- round-1 scalar fallback ----------------
__global__ __launch_bounds__(256) void fb2_kernel(
    const float* __restrict__ lv2, const int* __restrict__ hidx,
    float* __restrict__ out)
{
    int t = blockIdx.x * 256 + threadIdx.x;
    int x  = t & 127;
    int y  = (t >> 7) & 127;
    int bc = t >> 14;
    int b  = t >> 21;
    const int*   hb  = hidx + (b << 14);
    const float* src = lv2 + ((long)bc << 14);
    float acc = 0.f;
#pragma unroll
    for (int da = -1; da <= 1; ++da) {
        int a = y + da;
        if ((unsigned)a >= 128u) continue;
#pragma unroll
        for (int de = -1; de <= 1; ++de) {
            int e = x + de;
            if ((unsigned)e >= 128u) continue;
            int p  = hb[(a << 7) + e];
            int sr = (p >> 7) - da;
            int sc = (p & 127) - de;
            if ((unsigned)sr < 128u && (unsigned)sc < 128u)
                acc += src[(sr << 7) + sc];
        }
    }
    out[t] = acc * (1.f / 9.f);
}

__global__ __launch_bounds__(256) void fb1_kernel(
    const float* __restrict__ lv1, const int* __restrict__ hidx,
    float* __restrict__ out)
{
    int t = blockIdx.x * 256 + threadIdx.x;
    int X  = t & 255;
    int Y  = (t >> 8) & 255;
    int bc = t >> 16;
    int b  = t >> 22;
    const int*   hb  = hidx + (b << 14);
    const float* src = lv1 + ((long)bc << 16);
    int jyh = (Y + 2) >> 1;
    int jxh = (X + 2) >> 1;
    float acc = 0.f;
#pragma unroll
    for (int ka = 0; ka < 3; ++ka) {
        int jy = jyh - ka;
        if ((unsigned)jy >= 128u) continue;
        int dy = Y - 2 * jy;
#pragma unroll
        for (int kb = 0; kb < 3; ++kb) {
            int jx = jxh - kb;
            if ((unsigned)jx >= 128u) continue;
            int dx = X - 2 * jx;
            int p  = hb[(jy << 7) + jx];
            int sr = 2 * (p >> 7) + dy;
            int sc = 2 * (p & 127) + dx;
            if ((unsigned)sr < 256u && (unsigned)sc < 256u)
                acc += src[(sr << 8) + sc];
        }
    }
    out[t] = acc * (1.f / 9.f);
}

extern "C" void kernel_launch(void* const* d_in, const int* in_sizes, int n_in,
                              void* d_out, int out_size, void* d_ws, size_t ws_size,
                              hipStream_t stream)
{
    const float* lv1  = (const float*)d_in[0];
    const float* lv2  = (const float*)d_in[1];
    const int*   hidx = (const int*)d_in[2];
    float* out = (float*)d_out;

    if (ws_size >= WS_NEED) {
        __half* ws2T = (__half*)d_ws;
        __half* ws1T = ws2T + N2;
        prep_kernel<<<1536, 256, 0, stream>>>(lv1, lv2, ws2T, ws1T);
        mains_kernel<<<3072, 256, 0, stream>>>(ws2T, ws1T, hidx, out);
    } else {
        fb2_kernel<<<N2 / 256, 256, 0, stream>>>(lv2, hidx, out);
        fb1_kernel<<<N1 / 256, 256, 0, stream>>>(lv1, hidx, out + N2);
    }
}